// Round 1
// baseline (103.657 us; speedup 1.0000x reference)
//
#include <hip/hip_runtime.h>
#include <hip/hip_bf16.h>

#define B_  16
#define C_  3
#define H_  384
#define W_  1280
#define HW_ (H_ * W_)
#define EPS_ 1e-7f

__global__ __launch_bounds__(256) void ImageWarp_kernel(
    const float* __restrict__ src,     // [B,C,H,W]
    const float* __restrict__ depth,   // [B,1,H,W]
    const float* __restrict__ pose,    // [3,4]
    const float* __restrict__ Kb,      // [B,4,4]
    const float* __restrict__ Kinv,    // [B,4,4]
    float* __restrict__ out)           // [B,C,H,W]
{
    __shared__ float M[12];  // A (row-major 3x3) then t (3)

    const int idx = blockIdx.x * 256 + threadIdx.x;
    const int b   = idx / HW_;          // uniform per block (HW_ % 256 == 0)
    const int rem = idx - b * HW_;
    const int y   = rem / W_;           // uniform per block (W_ % 256 == 0)
    const int x   = rem - y * W_;

    if (threadIdx.x == 0) {
        // T = [[pose],[0,0,0,1]]
        float T[4][4];
        #pragma unroll
        for (int i = 0; i < 3; ++i)
            #pragma unroll
            for (int j = 0; j < 4; ++j)
                T[i][j] = pose[i * 4 + j];
        T[3][0] = 0.f; T[3][1] = 0.f; T[3][2] = 0.f; T[3][3] = 1.f;

        const float* K = Kb + b * 16;
        // P = (K @ T) rows 0..2
        float P[3][4];
        #pragma unroll
        for (int i = 0; i < 3; ++i) {
            #pragma unroll
            for (int j = 0; j < 4; ++j) {
                float s = 0.f;
                #pragma unroll
                for (int k = 0; k < 4; ++k) s += K[i * 4 + k] * T[k][j];
                P[i][j] = s;
            }
        }
        const float* Ki = Kinv + b * 16;
        // A = P[:, :3] @ Kinv[:3, :3]
        #pragma unroll
        for (int i = 0; i < 3; ++i) {
            #pragma unroll
            for (int j = 0; j < 3; ++j) {
                float s = 0.f;
                #pragma unroll
                for (int k = 0; k < 3; ++k) s += P[i][k] * Ki[k * 4 + j];
                M[i * 3 + j] = s;
            }
        }
        M[9]  = P[0][3];
        M[10] = P[1][3];
        M[11] = P[2][3];
    }
    __syncthreads();

    const float A00 = M[0], A01 = M[1], A02 = M[2];
    const float A10 = M[3], A11 = M[4], A12 = M[5];
    const float A20 = M[6], A21 = M[7], A22 = M[8];
    const float t0  = M[9], t1  = M[10], t2 = M[11];

    const float fx = (float)x, fy = (float)y;
    const float d  = depth[b * HW_ + rem];

    // cp = d * (A @ [x,y,1]) + t
    const float cpx = fmaf(d, fmaf(A00, fx, fmaf(A01, fy, A02)), t0);
    const float cpy = fmaf(d, fmaf(A10, fx, fmaf(A11, fy, A12)), t1);
    const float cpz = fmaf(d, fmaf(A20, fx, fmaf(A21, fy, A22)), t2);

    const float inv = 1.0f / (cpz + EPS_);
    const float px  = cpx * inv;
    const float py  = cpy * inv;

    // Exactly mirror the reference's normalization + unnormalization chain.
    const float gx = (px / (float)(W_ - 1) - 0.5f) * 2.0f;
    const float gy = (py / (float)(H_ - 1) - 0.5f) * 2.0f;
    float ix = ((gx + 1.0f) * (float)W_ - 1.0f) * 0.5f;
    float iy = ((gy + 1.0f) * (float)H_ - 1.0f) * 0.5f;

    // border padding
    ix = fminf(fmaxf(ix, 0.0f), (float)(W_ - 1));
    iy = fminf(fmaxf(iy, 0.0f), (float)(H_ - 1));

    const float x0 = floorf(ix), y0 = floorf(iy);
    const float wx1 = ix - x0, wx0 = 1.0f - wx1;
    const float wy1 = iy - y0, wy0 = 1.0f - wy1;

    int x0i = (int)x0;
    int y0i = (int)y0;
    if (x0i < 0) x0i = 0; if (x0i > W_ - 1) x0i = W_ - 1;
    if (y0i < 0) y0i = 0; if (y0i > H_ - 1) y0i = H_ - 1;
    const int x1i = (x0i + 1 < W_ - 1) ? (x0i + 1) : (W_ - 1);
    const int y1i = (y0i + 1 < H_ - 1) ? (y0i + 1) : (H_ - 1);

    const float wa = wy0 * wx0, wb = wy0 * wx1;
    const float wc = wy1 * wx0, wd = wy1 * wx1;

    const int i00 = y0i * W_ + x0i;
    const int i01 = y0i * W_ + x1i;
    const int i10 = y1i * W_ + x0i;
    const int i11 = y1i * W_ + x1i;

    const float* im = src + (size_t)b * C_ * HW_;
    float*       ob = out + (size_t)b * C_ * HW_;

    #pragma unroll
    for (int c = 0; c < C_; ++c) {
        const float* ic = im + c * HW_;
        const float v = wa * ic[i00] + wb * ic[i01] + wc * ic[i10] + wd * ic[i11];
        ob[c * HW_ + rem] = v;
    }
}

extern "C" void kernel_launch(void* const* d_in, const int* in_sizes, int n_in,
                              void* d_out, int out_size, void* d_ws, size_t ws_size,
                              hipStream_t stream) {
    const float* src   = (const float*)d_in[0];
    const float* depth = (const float*)d_in[1];
    const float* pose  = (const float*)d_in[2];
    const float* Kb    = (const float*)d_in[3];
    const float* Kinv  = (const float*)d_in[4];
    float* out = (float*)d_out;

    const int total  = B_ * HW_;          // 7,864,320
    const int blocks = total / 256;       // 30,720
    ImageWarp_kernel<<<blocks, 256, 0, stream>>>(src, depth, pose, Kb, Kinv, out);
}

// Round 2
// 98.813 us; speedup vs baseline: 1.0490x; 1.0490x over previous
//
#include <hip/hip_runtime.h>
#include <hip/hip_bf16.h>

#define B_  16
#define C_  3
#define H_  384
#define W_  1280
#define HW_ (H_ * W_)
#define EPS_ 1e-7f
#define NBLK_ (B_ * HW_ / 256)   // 30720
#define PERXCD_ (NBLK_ / 8)      // 3840

__global__ __launch_bounds__(256) void ImageWarp_kernel(
    const float* __restrict__ src,     // [B,C,H,W]
    const float* __restrict__ depth,   // [B,1,H,W]
    const float* __restrict__ pose,    // [3,4]
    const float* __restrict__ Kb,      // [B,4,4]
    const float* __restrict__ Kinv,    // [B,4,4]
    float* __restrict__ out)           // [B,C,H,W]
{
    __shared__ float M[12];  // A (row-major 3x3) then t (3)

    // XCD-chunked swizzle: HW round-robins blockIdx.x % 8 across XCDs, so
    // give XCD k the contiguous logical chunk [k*PERXCD_, (k+1)*PERXCD_).
    // Each XCD then owns 2 whole batches -> every src row fetched by one L2.
    const int lb  = (blockIdx.x & 7) * PERXCD_ + (blockIdx.x >> 3);
    const int idx = lb * 256 + threadIdx.x;
    const int b   = idx / HW_;          // uniform per block (HW_ % 256 == 0)
    const int rem = idx - b * HW_;
    const int y   = rem / W_;           // uniform per block (W_ % 256 == 0)
    const int x   = rem - y * W_;

    if (threadIdx.x == 0) {
        // T = [[pose],[0,0,0,1]]
        float T[4][4];
        #pragma unroll
        for (int i = 0; i < 3; ++i)
            #pragma unroll
            for (int j = 0; j < 4; ++j)
                T[i][j] = pose[i * 4 + j];
        T[3][0] = 0.f; T[3][1] = 0.f; T[3][2] = 0.f; T[3][3] = 1.f;

        const float* K = Kb + b * 16;
        // P = (K @ T) rows 0..2
        float P[3][4];
        #pragma unroll
        for (int i = 0; i < 3; ++i) {
            #pragma unroll
            for (int j = 0; j < 4; ++j) {
                float s = 0.f;
                #pragma unroll
                for (int k = 0; k < 4; ++k) s += K[i * 4 + k] * T[k][j];
                P[i][j] = s;
            }
        }
        const float* Ki = Kinv + b * 16;
        // A = P[:, :3] @ Kinv[:3, :3]
        #pragma unroll
        for (int i = 0; i < 3; ++i) {
            #pragma unroll
            for (int j = 0; j < 3; ++j) {
                float s = 0.f;
                #pragma unroll
                for (int k = 0; k < 3; ++k) s += P[i][k] * Ki[k * 4 + j];
                M[i * 3 + j] = s;
            }
        }
        M[9]  = P[0][3];
        M[10] = P[1][3];
        M[11] = P[2][3];
    }
    __syncthreads();

    const float A00 = M[0], A01 = M[1], A02 = M[2];
    const float A10 = M[3], A11 = M[4], A12 = M[5];
    const float A20 = M[6], A21 = M[7], A22 = M[8];
    const float t0  = M[9], t1  = M[10], t2 = M[11];

    const float fx = (float)x, fy = (float)y;
    const float d  = __builtin_nontemporal_load(&depth[b * HW_ + rem]);

    // cp = d * (A @ [x,y,1]) + t
    const float cpx = fmaf(d, fmaf(A00, fx, fmaf(A01, fy, A02)), t0);
    const float cpy = fmaf(d, fmaf(A10, fx, fmaf(A11, fy, A12)), t1);
    const float cpz = fmaf(d, fmaf(A20, fx, fmaf(A21, fy, A22)), t2);

    const float inv = 1.0f / (cpz + EPS_);
    const float px  = cpx * inv;
    const float py  = cpy * inv;

    // Exactly mirror the reference's normalization + unnormalization chain.
    const float gx = (px / (float)(W_ - 1) - 0.5f) * 2.0f;
    const float gy = (py / (float)(H_ - 1) - 0.5f) * 2.0f;
    float ix = ((gx + 1.0f) * (float)W_ - 1.0f) * 0.5f;
    float iy = ((gy + 1.0f) * (float)H_ - 1.0f) * 0.5f;

    // border padding
    ix = fminf(fmaxf(ix, 0.0f), (float)(W_ - 1));
    iy = fminf(fmaxf(iy, 0.0f), (float)(H_ - 1));

    const float x0 = floorf(ix), y0 = floorf(iy);
    const float wx1 = ix - x0, wx0 = 1.0f - wx1;
    const float wy1 = iy - y0, wy0 = 1.0f - wy1;

    int x0i = (int)x0;
    int y0i = (int)y0;
    if (x0i < 0) x0i = 0; if (x0i > W_ - 1) x0i = W_ - 1;
    if (y0i < 0) y0i = 0; if (y0i > H_ - 1) y0i = H_ - 1;
    const int x1i = (x0i + 1 < W_ - 1) ? (x0i + 1) : (W_ - 1);
    const int y1i = (y0i + 1 < H_ - 1) ? (y0i + 1) : (H_ - 1);

    const float wa = wy0 * wx0, wb = wy0 * wx1;
    const float wc = wy1 * wx0, wd = wy1 * wx1;

    const int i00 = y0i * W_ + x0i;
    const int i01 = y0i * W_ + x1i;
    const int i10 = y1i * W_ + x0i;
    const int i11 = y1i * W_ + x1i;

    const float* im = src + (size_t)b * C_ * HW_;
    float*       ob = out + (size_t)b * C_ * HW_;

    #pragma unroll
    for (int c = 0; c < C_; ++c) {
        const float* ic = im + c * HW_;
        const float v = wa * ic[i00] + wb * ic[i01] + wc * ic[i10] + wd * ic[i11];
        __builtin_nontemporal_store(v, &ob[c * HW_ + rem]);
    }
}

extern "C" void kernel_launch(void* const* d_in, const int* in_sizes, int n_in,
                              void* d_out, int out_size, void* d_ws, size_t ws_size,
                              hipStream_t stream) {
    const float* src   = (const float*)d_in[0];
    const float* depth = (const float*)d_in[1];
    const float* pose  = (const float*)d_in[2];
    const float* Kb    = (const float*)d_in[3];
    const float* Kinv  = (const float*)d_in[4];
    float* out = (float*)d_out;

    ImageWarp_kernel<<<NBLK_, 256, 0, stream>>>(src, depth, pose, Kb, Kinv, out);
}

// Round 3
// 74.649 us; speedup vs baseline: 1.3886x; 1.3237x over previous
//
#include <hip/hip_runtime.h>
#include <hip/hip_bf16.h>

#define B_  16
#define C_  3
#define H_  384
#define W_  1280
#define HW_ (H_ * W_)
#define EPS_ 1e-7f
#define NBLK_ (B_ * HW_ / 256)   // 30720
#define PERXCD_ (NBLK_ / 8)      // 3840

struct F2 { float x, y; };

__device__ __forceinline__ F2 ldpair(const float* p) {
    // Unaligned 8B load: clang emits global_load_dwordx2 (unaligned-access
    // mode on gfx9+); halves the TA line-request count vs two dword gathers.
    F2 r;
    __builtin_memcpy(&r, p, sizeof(F2));
    return r;
}

__global__ __launch_bounds__(256) void ImageWarp_kernel(
    const float* __restrict__ src,     // [B,C,H,W]
    const float* __restrict__ depth,   // [B,1,H,W]
    const float* __restrict__ pose,    // [3,4]
    const float* __restrict__ Kb,      // [B,4,4]
    const float* __restrict__ Kinv,    // [B,4,4]
    float* __restrict__ out)           // [B,C,H,W]
{
    __shared__ float M[12];  // A (row-major 3x3) then t (3)

    // XCD-chunked swizzle: each XCD owns 2 whole batches -> src rows are
    // fetched from HBM by exactly one XCD's L2 (R1: FETCH 296->61 MB).
    const int lb  = (blockIdx.x & 7) * PERXCD_ + (blockIdx.x >> 3);
    const int idx = lb * 256 + threadIdx.x;
    const int b   = idx / HW_;          // uniform per block (HW_ % 256 == 0)
    const int rem = idx - b * HW_;
    const int y   = rem / W_;           // uniform per block (W_ % 256 == 0)
    const int x   = rem - y * W_;

    if (threadIdx.x == 0) {
        float T[4][4];
        #pragma unroll
        for (int i = 0; i < 3; ++i)
            #pragma unroll
            for (int j = 0; j < 4; ++j)
                T[i][j] = pose[i * 4 + j];
        T[3][0] = 0.f; T[3][1] = 0.f; T[3][2] = 0.f; T[3][3] = 1.f;

        const float* K = Kb + b * 16;
        float P[3][4];
        #pragma unroll
        for (int i = 0; i < 3; ++i) {
            #pragma unroll
            for (int j = 0; j < 4; ++j) {
                float s = 0.f;
                #pragma unroll
                for (int k = 0; k < 4; ++k) s += K[i * 4 + k] * T[k][j];
                P[i][j] = s;
            }
        }
        const float* Ki = Kinv + b * 16;
        #pragma unroll
        for (int i = 0; i < 3; ++i) {
            #pragma unroll
            for (int j = 0; j < 3; ++j) {
                float s = 0.f;
                #pragma unroll
                for (int k = 0; k < 3; ++k) s += P[i][k] * Ki[k * 4 + j];
                M[i * 3 + j] = s;
            }
        }
        M[9]  = P[0][3];
        M[10] = P[1][3];
        M[11] = P[2][3];
    }
    __syncthreads();

    const float A00 = M[0], A01 = M[1], A02 = M[2];
    const float A10 = M[3], A11 = M[4], A12 = M[5];
    const float A20 = M[6], A21 = M[7], A22 = M[8];
    const float t0  = M[9], t1  = M[10], t2 = M[11];

    const float fx = (float)x, fy = (float)y;
    const float d  = __builtin_nontemporal_load(&depth[b * HW_ + rem]);

    const float cpx = fmaf(d, fmaf(A00, fx, fmaf(A01, fy, A02)), t0);
    const float cpy = fmaf(d, fmaf(A10, fx, fmaf(A11, fy, A12)), t1);
    const float cpz = fmaf(d, fmaf(A20, fx, fmaf(A21, fy, A22)), t2);

    const float inv = 1.0f / (cpz + EPS_);
    const float px  = cpx * inv;
    const float py  = cpy * inv;

    const float gx = (px / (float)(W_ - 1) - 0.5f) * 2.0f;
    const float gy = (py / (float)(H_ - 1) - 0.5f) * 2.0f;
    float ix = ((gx + 1.0f) * (float)W_ - 1.0f) * 0.5f;
    float iy = ((gy + 1.0f) * (float)H_ - 1.0f) * 0.5f;

    ix = fminf(fmaxf(ix, 0.0f), (float)(W_ - 1));
    iy = fminf(fmaxf(iy, 0.0f), (float)(H_ - 1));

    const float x0 = floorf(ix), y0 = floorf(iy);
    const float wx1 = ix - x0, wx0 = 1.0f - wx1;
    const float wy1 = iy - y0, wy0 = 1.0f - wy1;

    int x0i = (int)x0;
    int y0i = (int)y0;
    if (x0i < 0) x0i = 0; if (x0i > W_ - 1) x0i = W_ - 1;
    if (y0i < 0) y0i = 0; if (y0i > H_ - 1) y0i = H_ - 1;
    const int y1i = (y0i + 1 < H_ - 1) ? (y0i + 1) : (H_ - 1);

    // Pair base: guarantee [xb, xb+1] in-bounds. When x0i == W-1 (clamped,
    // wx1 == 0), shift base left; both taps then read .y == src[W-1].
    const int  xb = (x0i < W_ - 1) ? x0i : (W_ - 2);
    const bool hi = (x0i != xb);

    const float wa = wy0 * wx0, wb = wy0 * wx1;
    const float wc = wy1 * wx0, wd = wy1 * wx1;

    const int i0 = y0i * W_ + xb;
    const int i1 = y1i * W_ + xb;

    const float* im = src + (size_t)b * C_ * HW_;
    float*       ob = out + (size_t)b * C_ * HW_;

    // Issue all 6 pair-gathers up front for ILP.
    const F2 p0a = ldpair(im + 0 * HW_ + i0);
    const F2 p0b = ldpair(im + 0 * HW_ + i1);
    const F2 p1a = ldpair(im + 1 * HW_ + i0);
    const F2 p1b = ldpair(im + 1 * HW_ + i1);
    const F2 p2a = ldpair(im + 2 * HW_ + i0);
    const F2 p2b = ldpair(im + 2 * HW_ + i1);

    {
        const float Ia = hi ? p0a.y : p0a.x, Ib = p0a.y;
        const float Ic = hi ? p0b.y : p0b.x, Id = p0b.y;
        __builtin_nontemporal_store(wa * Ia + wb * Ib + wc * Ic + wd * Id,
                                    &ob[0 * HW_ + rem]);
    }
    {
        const float Ia = hi ? p1a.y : p1a.x, Ib = p1a.y;
        const float Ic = hi ? p1b.y : p1b.x, Id = p1b.y;
        __builtin_nontemporal_store(wa * Ia + wb * Ib + wc * Ic + wd * Id,
                                    &ob[1 * HW_ + rem]);
    }
    {
        const float Ia = hi ? p2a.y : p2a.x, Ib = p2a.y;
        const float Ic = hi ? p2b.y : p2b.x, Id = p2b.y;
        __builtin_nontemporal_store(wa * Ia + wb * Ib + wc * Ic + wd * Id,
                                    &ob[2 * HW_ + rem]);
    }
}

extern "C" void kernel_launch(void* const* d_in, const int* in_sizes, int n_in,
                              void* d_out, int out_size, void* d_ws, size_t ws_size,
                              hipStream_t stream) {
    const float* src   = (const float*)d_in[0];
    const float* depth = (const float*)d_in[1];
    const float* pose  = (const float*)d_in[2];
    const float* Kb    = (const float*)d_in[3];
    const float* Kinv  = (const float*)d_in[4];
    float* out = (float*)d_out;

    ImageWarp_kernel<<<NBLK_, 256, 0, stream>>>(src, depth, pose, Kb, Kinv, out);
}